// Round 1
// 3698.424 us; speedup vs baseline: 1.3640x; 1.3640x over previous
//
#include <hip/hip_runtime.h>

#define HD 1024
#define ID 2048
#define NCHUNK 32
#define CHUNKSZ 64
#define NB 8
#define SEQ 2048
#define ROWS 512
#define MTOT 524288.0f
#define EPSF 1e-6f

typedef unsigned short u16;
typedef unsigned int u32;
typedef short bf16x8 __attribute__((ext_vector_type(8)));
typedef float f32x4 __attribute__((ext_vector_type(4)));

#define GATHER(r, c) ((((r) >> 6) * SEQ) + ((c) * CHUNKSZ) + ((r) & 63))

__device__ __forceinline__ float sigmoidf_(float x) { return 1.f / (1.f + expf(-x)); }
__device__ __forceinline__ float siluf_(float x)    { return x / (1.f + expf(-x)); }
__device__ __forceinline__ float silu_d_(float z)   { float sg = sigmoidf_(z); return sg * (1.f + z * (1.f - sg)); }

__device__ __forceinline__ u16 f2b(float f) {
  union { float f; u32 u; } v; v.f = f;
  return (u16)((v.u + 0x7fffu + ((v.u >> 16) & 1u)) >> 16);
}
__device__ __forceinline__ float b2f(u16 b) {
  union { u32 u; float f; } v; v.u = ((u32)b) << 16; return v.f;
}
__device__ __forceinline__ u32 pack2(float a, float b) { return (u32)f2b(a) | ((u32)f2b(b) << 16); }

__device__ __forceinline__ float block_reduce_sum(float v, float* s4) {
  #pragma unroll
  for (int off = 32; off > 0; off >>= 1) v += __shfl_down(v, off);
  int lane = threadIdx.x & 63, wid = threadIdx.x >> 6;
  if (lane == 0) s4[wid] = v;
  __syncthreads();
  float r = s4[0] + s4[1] + s4[2] + s4[3];
  __syncthreads();
  return r;
}

// ---------------------------------------------------------------------------
// LDS staging: NT = row-major uint4 store; TN = scatter-transpose (16 u16).
// LDS layout is identical for both: [tile_row][k], stride 72 u16.
// ---------------------------------------------------------------------------
template<bool T>
__device__ __forceinline__ void stage64(u16* S, int srow, int c16, const uint4& r0, const uint4& r1) {
  if (!T) {
    *(uint4*)(S + srow * 72 + c16)     = r0;
    *(uint4*)(S + srow * 72 + c16 + 8) = r1;
  } else {
    const u16* e0 = (const u16*)&r0;
    const u16* e1 = (const u16*)&r1;
    #pragma unroll
    for (int e = 0; e < 8; ++e) S[(c16 + e) * 72 + srow] = e0[e];
    #pragma unroll
    for (int e = 0; e < 8; ++e) S[(c16 + 8 + e) * 72 + srow] = e1[e];
  }
}

// ---------------------------------------------------------------------------
// 64x64-tile BK=64 GEMM core, double-buffered LDS, 1 barrier per K-step.
// AT/BT: operand stored transposed (K-major) -> scatter-staged.
// NT A: A[(m0+row)*lda + k]   (chA>=0: row gathered per GATHER)
// TN A: A[k*lda + m0+col]
// NT B: B[(n0+row)*ldb + k]
// TN B: B[k*ldb + n0+col]     (chB>=0: k-row gathered per GATHER)
// ---------------------------------------------------------------------------
template<bool AT, bool BT>
__device__ __forceinline__ void gemm64_db(
    f32x4 (&acc)[2][2], const u16* __restrict__ A, const u16* __restrict__ B,
    int K, int m0, int n0, int lda, int ldb, int chA, int chB,
    u16* As, u16* Bs)
{
  const int tid = threadIdx.x;
  const int lane = tid & 63, wave = tid >> 6;
  const int wr = wave >> 1, wc = wave & 1;
  const int l15 = lane & 15, q = lane >> 4;
  const int srow = tid >> 2, c16 = (tid & 3) * 16;

  const u16* Ap; size_t Astep;
  if (!AT) {
    int r = m0 + srow;
    if (chA >= 0) r = GATHER(r, chA);
    Ap = A + (size_t)r * lda + c16;
    Astep = 64;
  } else {
    Ap = A + (size_t)srow * lda + m0 + c16;
    Astep = (size_t)64 * lda;
  }
  const u16* Bp; size_t Bstep;
  if (!BT) {
    Bp = B + (size_t)(n0 + srow) * ldb + c16;
    Bstep = 64;
  } else {
    if (chB >= 0) { Bp = B + ((size_t)chB * CHUNKSZ + srow) * ldb + n0 + c16; Bstep = (size_t)SEQ * ldb; }
    else          { Bp = B + (size_t)srow * ldb + n0 + c16;                   Bstep = (size_t)64 * ldb; }
  }

  // prologue: stage tile 0 into buffer 0
  uint4 ra0 = *(const uint4*)Ap, ra1 = *(const uint4*)(Ap + 8);
  uint4 rb0 = *(const uint4*)Bp, rb1 = *(const uint4*)(Bp + 8);
  stage64<AT>(As, srow, c16, ra0, ra1);
  stage64<BT>(Bs, srow, c16, rb0, rb1);

  const int nt = K >> 6;
  int cur = 0;
  for (int t = 0; t < nt; ++t) {
    if (t + 1 < nt) {           // issue next-tile loads before the barrier
      Ap += Astep; Bp += Bstep;
      ra0 = *(const uint4*)Ap; ra1 = *(const uint4*)(Ap + 8);
      rb0 = *(const uint4*)Bp; rb1 = *(const uint4*)(Bp + 8);
    }
    __syncthreads();            // buf[cur] visible; prev reads of buf[cur^1] done
    const u16* Ac = As + cur * (64 * 72);
    const u16* Bc = Bs + cur * (64 * 72);
    #pragma unroll
    for (int ks = 0; ks < 2; ++ks) {
      bf16x8 af[2], bg[2];
      #pragma unroll
      for (int i = 0; i < 2; ++i) af[i] = *(const bf16x8*)&Ac[(wr * 32 + i * 16 + l15) * 72 + ks * 32 + q * 8];
      #pragma unroll
      for (int j = 0; j < 2; ++j) bg[j] = *(const bf16x8*)&Bc[(wc * 32 + j * 16 + l15) * 72 + ks * 32 + q * 8];
      #pragma unroll
      for (int i = 0; i < 2; ++i)
        #pragma unroll
        for (int j = 0; j < 2; ++j)
          acc[i][j] = __builtin_amdgcn_mfma_f32_16x16x32_bf16(af[i], bg[j], acc[i][j], 0, 0, 0);
    }
    if (t + 1 < nt) {           // write next tile into the other buffer
      stage64<AT>(As + (cur ^ 1) * (64 * 72), srow, c16, ra0, ra1);
      stage64<BT>(Bs + (cur ^ 1) * (64 * 72), srow, c16, rb0, rb1);
    }
    cur ^= 1;
  }
}

// fwd MLP layer-0: C = zfw fp32, Cb = f2b(silu(acc))
__global__ __launch_bounds__(256) void gemm64_fwd(
    float* __restrict__ C, u16* __restrict__ Cb,
    const u16* __restrict__ A, const u16* __restrict__ B, int N, int K, int chunk)
{
  __shared__ __align__(16) u16 As[2 * 64 * 72];
  __shared__ __align__(16) u16 Bs[2 * 64 * 72];
  const int m0 = blockIdx.y * 64, n0 = blockIdx.x * 64;
  f32x4 acc[2][2] = {};
  gemm64_db<false, false>(acc, A, B, K, m0, n0, K, K, chunk, -1, As, Bs);
  const int lane = threadIdx.x & 63, wave = threadIdx.x >> 6;
  const int wr = wave >> 1, wc = wave & 1;
  const int l15 = lane & 15, q = lane >> 4;
  #pragma unroll
  for (int i = 0; i < 2; ++i) {
    int r = m0 + wr * 32 + i * 16 + q * 4;
    #pragma unroll
    for (int j = 0; j < 2; ++j) {
      int col = n0 + wc * 32 + j * 16 + l15;
      #pragma unroll
      for (int t = 0; t < 4; ++t) {
        float v = acc[i][j][t];
        size_t o = (size_t)(r + t) * N + col;
        C[o] = v;
        Cb[o] = f2b(siluf_(v));
      }
    }
  }
}

// dH: Cb = f2b(acc * silu'(Z)); B = W1_bf read TN (K-major)
__global__ __launch_bounds__(256) void gemm64_dh(
    u16* __restrict__ Cb, const u16* __restrict__ A, const u16* __restrict__ B,
    const float* __restrict__ Z, int N, int K)
{
  __shared__ __align__(16) u16 As[2 * 64 * 72];
  __shared__ __align__(16) u16 Bs[2 * 64 * 72];
  const int m0 = blockIdx.y * 64, n0 = blockIdx.x * 64;
  f32x4 acc[2][2] = {};
  gemm64_db<false, true>(acc, A, B, K, m0, n0, K, N, -1, -1, As, Bs);
  const int lane = threadIdx.x & 63, wave = threadIdx.x >> 6;
  const int wr = wave >> 1, wc = wave & 1;
  const int l15 = lane & 15, q = lane >> 4;
  #pragma unroll
  for (int i = 0; i < 2; ++i) {
    int r = m0 + wr * 32 + i * 16 + q * 4;
    #pragma unroll
    for (int j = 0; j < 2; ++j) {
      int col = n0 + wc * 32 + j * 16 + l15;
      #pragma unroll
      for (int t = 0; t < 4; ++t) {
        size_t o = (size_t)(r + t) * N + col;
        Cb[o] = f2b(acc[i][j][t] * silu_d_(Z[o]));
      }
    }
  }
}

// both weight-grad GEMMs (TN, transpose fused into staging) + Gln blocks.
// blocks [0,512): Gw1 = dY^T @ hfw; [512,1024): Gw0 = dH^T @ k_c (gathered);
// [1024,1056): Gln[j] = sum_r g*y*srow. All ||.||^2 -> nsqc.
__global__ __launch_bounds__(256) void gemm_grads(
    float* __restrict__ Gw1, const u16* __restrict__ dY, const u16* __restrict__ hfw,
    float* __restrict__ Gw0, const u16* __restrict__ dH, const u16* __restrict__ kall,
    int c, const float* __restrict__ g, const float* __restrict__ y,
    const float* __restrict__ srow, float* __restrict__ Gln, float* __restrict__ nsqc)
{
  __shared__ __align__(16) u16 As[2 * 64 * 72];
  __shared__ __align__(16) u16 Bs[2 * 64 * 72];
  __shared__ float s4[4];
  int bid = blockIdx.x;
  const int tid = threadIdx.x;
  if (bid >= 1024) {
    // ---- Gln path: 32 blocks x 32 cols, rows split 8-ways across threads ----
    int j = (bid - 1024) * 32 + (tid & 31);
    int rg = tid >> 5;
    float acc = 0.f;
    #pragma unroll 4
    for (int i = 0; i < 64; ++i) {
      int r = rg * 64 + i;
      size_t o = (size_t)r * HD + j;
      acc += g[o] * y[o] * srow[r];
    }
    float* part = (float*)As;       // [8][32]
    part[rg * 32 + (tid & 31)] = acc;
    __syncthreads();
    if (tid < 32) {
      float tot = 0.f;
      #pragma unroll
      for (int k = 0; k < 8; ++k) tot += part[k * 32 + tid];
      Gln[j] = tot;
      float sq = tot * tot;
      #pragma unroll
      for (int off = 16; off > 0; off >>= 1) sq += __shfl_down(sq, off);
      if (tid == 0) atomicAdd(nsqc, sq);
    }
    return;
  }
  float* C; const u16* A; const u16* B; int N, m0, n0, lda, ldb, chB;
  if (bid < 512) { A = dY; B = hfw;  C = Gw1; N = ID; lda = HD; ldb = ID; chB = -1; m0 = (bid >> 5) * 64; n0 = (bid & 31) * 64; }
  else { bid -= 512; A = dH; B = kall; C = Gw0; N = HD; lda = ID; ldb = HD; chB = c; m0 = (bid >> 4) * 64; n0 = (bid & 15) * 64; }
  f32x4 acc[2][2] = {};
  gemm64_db<true, true>(acc, A, B, ROWS, m0, n0, lda, ldb, -1, chB, As, Bs);
  const int lane = tid & 63, wave = tid >> 6;
  const int wr = wave >> 1, wc = wave & 1;
  const int l15 = lane & 15, q = lane >> 4;
  float ssq = 0.f;
  #pragma unroll
  for (int i = 0; i < 2; ++i) {
    int r = m0 + wr * 32 + i * 16 + q * 4;
    #pragma unroll
    for (int j = 0; j < 2; ++j) {
      int col = n0 + wc * 32 + j * 16 + l15;
      #pragma unroll
      for (int t = 0; t < 4; ++t) {
        float v = acc[i][j][t];
        C[(size_t)(r + t) * N + col] = v;
        ssq += v * v;
      }
    }
  }
  float tot = block_reduce_sum(ssq, s4);
  if (tid == 0) atomicAdd(nsqc, tot);
}

// 32x64-tile BK=64 NT GEMM (128 threads), double-buffered: y = hfw @ W1^T
__global__ __launch_bounds__(128) void gemm_y32(
    float* __restrict__ C, const u16* __restrict__ A, const u16* __restrict__ B,
    int N, int K)
{
  __shared__ __align__(16) u16 As[2 * 32 * 72];
  __shared__ __align__(16) u16 Bs[2 * 64 * 72];
  const int tid = threadIdx.x;
  const int lane = tid & 63, wc = tid >> 6;
  const int l15 = lane & 15, q = lane >> 4;
  const int m0 = blockIdx.y * 32, n0 = blockIdx.x * 64;

  const int arow = tid >> 2, ac16 = (tid & 3) * 16;   // 32 rows x 64 cols
  const int brow = tid >> 1, bc32 = (tid & 1) * 32;   // 64 rows x 64 cols
  const u16* Ap = A + (size_t)(m0 + arow) * K + ac16;
  const u16* Bp = B + (size_t)(n0 + brow) * K + bc32;

  uint4 ra0 = *(const uint4*)Ap, ra1 = *(const uint4*)(Ap + 8);
  uint4 rb0 = *(const uint4*)Bp, rb1 = *(const uint4*)(Bp + 8);
  uint4 rb2 = *(const uint4*)(Bp + 16), rb3 = *(const uint4*)(Bp + 24);
  {
    u16* Aw = As + arow * 72 + ac16;
    u16* Bw = Bs + brow * 72 + bc32;
    *(uint4*)Aw = ra0; *(uint4*)(Aw + 8) = ra1;
    *(uint4*)Bw = rb0; *(uint4*)(Bw + 8) = rb1;
    *(uint4*)(Bw + 16) = rb2; *(uint4*)(Bw + 24) = rb3;
  }

  f32x4 acc[2][2] = {};
  const int nt = K >> 6;
  int cur = 0;
  for (int t = 0; t < nt; ++t) {
    if (t + 1 < nt) {
      Ap += 64; Bp += 64;
      ra0 = *(const uint4*)Ap; ra1 = *(const uint4*)(Ap + 8);
      rb0 = *(const uint4*)Bp; rb1 = *(const uint4*)(Bp + 8);
      rb2 = *(const uint4*)(Bp + 16); rb3 = *(const uint4*)(Bp + 24);
    }
    __syncthreads();
    const u16* Ac = As + cur * (32 * 72);
    const u16* Bc = Bs + cur * (64 * 72);
    #pragma unroll
    for (int ks = 0; ks < 2; ++ks) {
      bf16x8 af[2], bg[2];
      #pragma unroll
      for (int i = 0; i < 2; ++i) af[i] = *(const bf16x8*)&Ac[(i * 16 + l15) * 72 + ks * 32 + q * 8];
      #pragma unroll
      for (int j = 0; j < 2; ++j) bg[j] = *(const bf16x8*)&Bc[(wc * 32 + j * 16 + l15) * 72 + ks * 32 + q * 8];
      #pragma unroll
      for (int i = 0; i < 2; ++i)
        #pragma unroll
        for (int j = 0; j < 2; ++j)
          acc[i][j] = __builtin_amdgcn_mfma_f32_16x16x32_bf16(af[i], bg[j], acc[i][j], 0, 0, 0);
    }
    if (t + 1 < nt) {
      u16* Aw = As + (cur ^ 1) * (32 * 72) + arow * 72 + ac16;
      u16* Bw = Bs + (cur ^ 1) * (64 * 72) + brow * 72 + bc32;
      *(uint4*)Aw = ra0; *(uint4*)(Aw + 8) = ra1;
      *(uint4*)Bw = rb0; *(uint4*)(Bw + 8) = rb1;
      *(uint4*)(Bw + 16) = rb2; *(uint4*)(Bw + 24) = rb3;
    }
    cur ^= 1;
  }
  #pragma unroll
  for (int i = 0; i < 2; ++i) {
    int r = m0 + i * 16 + q * 4;
    #pragma unroll
    for (int j = 0; j < 2; ++j) {
      int col = n0 + wc * 32 + j * 16 + l15;
      #pragma unroll
      for (int t = 0; t < 4; ++t)
        C[(size_t)(r + t) * N + col] = acc[i][j][t];
    }
  }
}

// ---------------------------------------------------------------------------
// 128x128-tile BK=32 NT GEMM (stride-40 LDS).
// EPI 0: C fp32.  1: Cb = f2b(silu(acc)).  2: kv-mode — z=0: Cb=f2b(acc),
// z=1: Cb1=f2b(silu(acc)); B picked by z.
// ---------------------------------------------------------------------------
template<int EPI, bool AF32>
__global__ __launch_bounds__(256) void gemm128_t(
    float* __restrict__ C, u16* __restrict__ Cb, u16* __restrict__ Cb1,
    const u16* __restrict__ A, const float* __restrict__ Af,
    const u16* __restrict__ B0, const u16* __restrict__ B1,
    int M, int N, int K)
{
  __shared__ __align__(16) u16 As[128 * 40];
  __shared__ __align__(16) u16 Bs[128 * 40];
  const int tid = threadIdx.x;
  const int lane = tid & 63, wave = tid >> 6;
  const int wr = wave >> 1, wc = wave & 1;
  const int l15 = lane & 15, q = lane >> 4;
  const int m0 = blockIdx.y * 128, n0 = blockIdx.x * 128;
  const u16* B = (EPI == 2 && blockIdx.z) ? B1 : B0;

  f32x4 acc[4][4] = {};
  for (int k0 = 0; k0 < K; k0 += 32) {
    #pragma unroll
    for (int it = 0; it < 2; ++it) {
      int cid = tid + it * 256;
      int row = cid >> 2, c8 = (cid & 3) * 8;
      if (AF32) {
        const float* ap = Af + (size_t)(m0 + row) * K + k0 + c8;
        float4 f0 = *(const float4*)ap;
        float4 f1 = *(const float4*)(ap + 4);
        uint4 o; o.x = pack2(f0.x, f0.y); o.y = pack2(f0.z, f0.w);
        o.z = pack2(f1.x, f1.y); o.w = pack2(f1.z, f1.w);
        *(uint4*)&As[row * 40 + c8] = o;
      } else {
        *(uint4*)&As[row * 40 + c8] = *(const uint4*)&A[(size_t)(m0 + row) * K + k0 + c8];
      }
      *(uint4*)&Bs[row * 40 + c8] = *(const uint4*)&B[(size_t)(n0 + row) * K + k0 + c8];
    }
    __syncthreads();
    bf16x8 af[4], bg[4];
    #pragma unroll
    for (int i = 0; i < 4; ++i) af[i] = *(const bf16x8*)&As[(wr * 64 + i * 16 + l15) * 40 + q * 8];
    #pragma unroll
    for (int j = 0; j < 4; ++j) bg[j] = *(const bf16x8*)&Bs[(wc * 64 + j * 16 + l15) * 40 + q * 8];
    #pragma unroll
    for (int i = 0; i < 4; ++i)
      #pragma unroll
      for (int j = 0; j < 4; ++j)
        acc[i][j] = __builtin_amdgcn_mfma_f32_16x16x32_bf16(af[i], bg[j], acc[i][j], 0, 0, 0);
    __syncthreads();
  }
  #pragma unroll
  for (int i = 0; i < 4; ++i) {
    int r = m0 + wr * 64 + i * 16 + q * 4;
    #pragma unroll
    for (int j = 0; j < 4; ++j) {
      int col = n0 + wc * 64 + j * 16 + l15;
      #pragma unroll
      for (int t = 0; t < 4; ++t) {
        float v = acc[i][j][t];
        size_t o = (size_t)(r + t) * N + col;
        if (EPI == 0) C[o] = v;
        if (EPI == 1) Cb[o] = f2b(siluf_(v));
        if (EPI == 2) { if (blockIdx.z == 0) Cb[o] = f2b(v); else Cb1[o] = f2b(siluf_(v)); }
      }
    }
  }
}

// ---------------------------------------------------------------------------
// setup conversions
// ---------------------------------------------------------------------------
__global__ __launch_bounds__(256) void conv_f2b(u16* __restrict__ dst, const float* __restrict__ src, int n) {
  int i = (blockIdx.x * 256 + threadIdx.x) * 4;
  if (i < n) {
    float4 v = *(const float4*)&src[i];
    uint2 o; o.x = pack2(v.x, v.y); o.y = pack2(v.z, v.w);
    *(uint2*)&dst[i] = o;
  }
}

// ---------------------------------------------------------------------------
// small fused kernels
// ---------------------------------------------------------------------------
__global__ __launch_bounds__(256) void dots_kernel(
    const float* __restrict__ x, const float* __restrict__ aw,
    const float* __restrict__ tw, const float* __restrict__ ew,
    float* __restrict__ dA, float* __restrict__ dT, float* __restrict__ dE)
{
  int b = blockIdx.x >> 5, c = blockIdx.x & 31;
  const float* base = x + ((size_t)b * SEQ + (size_t)c * CHUNKSZ) * HD;
  float a = 0.f, t = 0.f, e = 0.f;
  for (int it = 0; it < 64; ++it) {
    int j = (it * 256 + threadIdx.x) * 4;
    float4 xv = *(const float4*)&base[j];
    float4 av = *(const float4*)&aw[j];
    float4 tv = *(const float4*)&tw[j];
    float4 ev = *(const float4*)&ew[j];
    a += xv.x * av.x + xv.y * av.y + xv.z * av.z + xv.w * av.w;
    t += xv.x * tv.x + xv.y * tv.y + xv.z * tv.z + xv.w * tv.w;
    e += xv.x * ev.x + xv.y * ev.y + xv.z * ev.z + xv.w * ev.w;
  }
  __shared__ float s4[4];
  a = block_reduce_sum(a, s4);
  t = block_reduce_sum(t, s4);
  e = block_reduce_sum(e, s4);
  if (threadIdx.x == 0) { dA[blockIdx.x] = a; dT[blockIdx.x] = t; dE[blockIdx.x] = e; }
}

__global__ __launch_bounds__(256) void coeff_kernel(
    const float* __restrict__ dA, const float* __restrict__ dT, const float* __restrict__ dE,
    float* __restrict__ betaA, float* __restrict__ etaA, float* __restrict__ thetaA)
{
  int t = threadIdx.x;
  if (t < 256) thetaA[t] = sigmoidf_(dT[t]) * 0.01f;
  if (t < 32) {
    float sa = 0.f, se = 0.f;
    for (int b = 0; b < NB; ++b) { sa += dA[b * 32 + t]; se += dE[b * 32 + t]; }
    betaA[t] = 1.f - sigmoidf_(sa / 8.f);
    etaA[t]  = sigmoidf_(se / 8.f);
  }
}

// dstb = f2b(rmsnorm(silu(src)) * nw); SRCB: src is bf16
template<bool SRCB>
__global__ __launch_bounds__(256) void post_norm(
    u16* __restrict__ dstb, const float* __restrict__ srcf,
    const u16* __restrict__ srcb, const float* __restrict__ nw)
{
  size_t off = (size_t)blockIdx.x * HD;
  float sv[4]; float ss = 0.f;
  #pragma unroll
  for (int i = 0; i < 4; ++i) {
    int j = i * 256 + threadIdx.x;
    float z = SRCB ? b2f(srcb[off + j]) : srcf[off + j];
    float s = siluf_(z);
    sv[i] = s; ss += s * s;
  }
  __shared__ float s4[4];
  ss = block_reduce_sum(ss, s4);
  float rs = rsqrtf(ss / (float)HD + EPSF);
  #pragma unroll
  for (int i = 0; i < 4; ++i) {
    int j = i * 256 + threadIdx.x;
    dstb[off + j] = f2b(sv[i] * rs * nw[j]);
  }
}

// per-row loss grad: k,v read as bf16 (gathered rows of k_all/v_all)
__global__ __launch_bounds__(256) void loss_grad(
    const float* __restrict__ y, const u16* __restrict__ kall, const u16* __restrict__ vall,
    const float* __restrict__ ln, const float* __restrict__ thetaA, int c,
    float* __restrict__ g, u16* __restrict__ dYbf, float* __restrict__ srow)
{
  int r = blockIdx.x;
  size_t off = (size_t)r * HD;
  size_t goff = (size_t)GATHER(r, c) * HD;
  float th = thetaA[(r >> 6) * 32 + c];
  float yv[4], lnv[4];
  float ss = 0.f;
  #pragma unroll
  for (int i = 0; i < 4; ++i) {
    int j = i * 256 + threadIdx.x;
    yv[i] = y[off + j];
    lnv[i] = ln[j];
    ss += yv[i] * yv[i];
  }
  __shared__ float s4[4];
  ss = block_reduce_sum(ss, s4);
  float s = rsqrtf(ss / (float)HD + EPSF);
  float coef = 2.f * th / MTOT;
  float gv[4]; float t = 0.f;
  #pragma unroll
  for (int i = 0; i < 4; ++i) {
    int j = i * 256 + threadIdx.x;
    float pred = b2f(kall[goff + j]) + yv[i] * s * lnv[i];
    float gg = coef * (pred - b2f(vall[goff + j]));
    gv[i] = gg;
    g[off + j] = gg;
    t += gg * lnv[i] * yv[i];
  }
  t = block_reduce_sum(t, s4);
  float c3 = s * s * s * t * (1.f / (float)HD);
  #pragma unroll
  for (int i = 0; i < 4; ++i) {
    int j = i * 256 + threadIdx.x;
    dYbf[off + j] = f2b(s * gv[i] * lnv[i] - c3 * yv[i]);
  }
  if (threadIdx.x == 0) srow[r] = s;
}

// merged update, flat: blocks [0,1024)=W1 (+w1b), [1024,2048)=W0 (+w0b), 2048=ln
__global__ __launch_bounds__(256) void update_all(
    float* __restrict__ mw0, float* __restrict__ sw0, const float* __restrict__ g0, u16* __restrict__ w0b,
    float* __restrict__ mw1, float* __restrict__ sw1, const float* __restrict__ g1, u16* __restrict__ w1b,
    float* __restrict__ mln, float* __restrict__ sln, const float* __restrict__ gl,
    const float* __restrict__ etaA, const float* __restrict__ betaA, int c,
    const float* __restrict__ nsqc)
{
  float clip = fminf(1.0f / (sqrtf(*nsqc) + 1e-6f), 1.0f);
  float eta = etaA[c], beta = betaA[c];
  int bid = blockIdx.x;
  if (bid < 2048) {
    float* mw; float* sw; const float* g; u16* wb; size_t i0;
    if (bid < 1024) { mw = mw1; sw = sw1; g = g1; wb = w1b; i0 = (size_t)bid * 2048; }
    else            { mw = mw0; sw = sw0; g = g0; wb = w0b; i0 = (size_t)(bid - 1024) * 2048; }
    i0 += (size_t)threadIdx.x * 8;
    u16 bb[8];
    #pragma unroll
    for (int h = 0; h < 2; ++h) {
      size_t i = i0 + h * 4;
      float4 s = *(float4*)&sw[i];
      float4 gg = *(const float4*)&g[i];
      float4 m = *(float4*)&mw[i];
      s.x = eta * s.x - clip * gg.x; m.x = beta * m.x + s.x;
      s.y = eta * s.y - clip * gg.y; m.y = beta * m.y + s.y;
      s.z = eta * s.z - clip * gg.z; m.z = beta * m.z + s.z;
      s.w = eta * s.w - clip * gg.w; m.w = beta * m.w + s.w;
      *(float4*)&sw[i] = s;
      *(float4*)&mw[i] = m;
      bb[h * 4 + 0] = f2b(m.x); bb[h * 4 + 1] = f2b(m.y);
      bb[h * 4 + 2] = f2b(m.z); bb[h * 4 + 3] = f2b(m.w);
    }
    *(uint4*)&wb[i0] = *(uint4*)bb;
  } else {
    int i = threadIdx.x * 4;
    #pragma unroll
    for (int k = 0; k < 4; ++k) {
      float ns = eta * sln[i + k] - clip * gl[i + k];
      sln[i + k] = ns;
      mln[i + k] = beta * mln[i + k] + ns;
    }
  }
}

// out = q + rmsnorm(y2)*ln, with q recomputed from zq (q = rmsnorm(silu(zq))*qn)
__global__ __launch_bounds__(256) void final_out_kernel(
    float* __restrict__ out, const float* __restrict__ zq, const float* __restrict__ y2,
    const float* __restrict__ qn, const float* __restrict__ ln)
{
  size_t off = (size_t)blockIdx.x * HD;
  float sv[4], yv[4];
  float ss1 = 0.f, ss2 = 0.f;
  #pragma unroll
  for (int i = 0; i < 4; ++i) {
    int j = i * 256 + threadIdx.x;
    float s = siluf_(zq[off + j]);
    sv[i] = s; ss1 += s * s;
    yv[i] = y2[off + j];
    ss2 += yv[i] * yv[i];
  }
  __shared__ float s4[4];
  ss1 = block_reduce_sum(ss1, s4);
  ss2 = block_reduce_sum(ss2, s4);
  float rs1 = rsqrtf(ss1 / (float)HD + EPSF);
  float rs2 = rsqrtf(ss2 / (float)HD + EPSF);
  #pragma unroll
  for (int i = 0; i < 4; ++i) {
    int j = i * 256 + threadIdx.x;
    out[off + j] = sv[i] * rs1 * qn[j] + yv[i] * rs2 * ln[j];
  }
}

// ---------------------------------------------------------------------------
// launch
// ---------------------------------------------------------------------------
extern "C" void kernel_launch(void* const* d_in, const int* in_sizes, int n_in,
                              void* d_out, int out_size, void* d_ws, size_t ws_size,
                              hipStream_t stream) {
  const float* x   = (const float*)d_in[0];
  const float* wq  = (const float*)d_in[1];
  const float* wk  = (const float*)d_in[2];
  const float* wv  = (const float*)d_in[3];
  const float* qn  = (const float*)d_in[4];
  const float* kn  = (const float*)d_in[5];
  const float* aw  = (const float*)d_in[6];
  const float* tw  = (const float*)d_in[7];
  const float* ew  = (const float*)d_in[8];
  const float* w0i = (const float*)d_in[9];
  const float* w1i = (const float*)d_in[10];
  const float* lni = (const float*)d_in[11];
  float* out = (float*)d_out;

  float* p = (float*)d_ws;
  auto alloc = [&](size_t n) { n = (n + 63) & ~(size_t)63; float* r = p; p += n; return r; };
  float* memW0  = alloc((size_t)ID * HD);
  float* memW1  = alloc((size_t)HD * ID);
  float* memLn  = alloc(HD);
  float* surpW0 = alloc((size_t)ID * HD);   // surpW0+surpW1 also: zk_all (setup), zq (retrieval)
  float* surpW1 = alloc((size_t)HD * ID);
  float* surpLn = alloc(HD);
  float* Gw0    = alloc((size_t)ID * HD);   // Gw0+Gw1 also: y2 (retrieval)
  float* Gw1    = alloc((size_t)HD * ID);
  float* Gln    = alloc(HD);
  float* zfw    = alloc((size_t)ROWS * ID); // zfw+ybuf+gbuf also: qb_bf (retrieval)
  float* ybuf   = alloc((size_t)ROWS * HD);
  float* gbuf   = alloc((size_t)ROWS * HD);
  float* srow   = alloc(ROWS);
  float* dotA   = alloc(256);
  float* dotT   = alloc(256);
  float* dotE   = alloc(256);
  float* betaA  = alloc(64);
  float* etaA   = alloc(64);
  float* thetaA = alloc(256);
  float* nsq    = alloc(64);

  u16* bp = (u16*)p;
  auto balloc = [&](size_t n) { n = (n + 63) & ~(size_t)63; u16* r = bp; bp += n; return r; };
  u16* wq_bf  = balloc((size_t)HD * HD);
  u16* wk_bf  = balloc((size_t)HD * HD);
  u16* wv_bf  = balloc((size_t)HD * HD);
  u16* W0_bf  = balloc((size_t)ID * HD);
  u16* W1_bf  = balloc((size_t)HD * ID);
  u16* k_all  = balloc((size_t)NB * SEQ * HD);  // also: h_bf (retrieval)
  u16* v_all  = balloc((size_t)NB * SEQ * HD);
  u16* hfw_bf = balloc((size_t)ROWS * ID);
  u16* dY_bf  = balloc((size_t)ROWS * HD);
  u16* dH_bf  = balloc((size_t)ROWS * ID);
  size_t needed = (size_t)((char*)bp - (char*)d_ws);
  if (needed > ws_size) return;

  u16* zk_all = (u16*)surpW0;  // 16.8M u16 fits in surpW0..Gw1 (33.5 MB); dead before memset

  // ---- setup ----
  conv_f2b<<<(HD * HD) / 1024, 256, 0, stream>>>(wq_bf, wq, HD * HD);
  conv_f2b<<<(HD * HD) / 1024, 256, 0, stream>>>(wk_bf, wk, HD * HD);
  conv_f2b<<<(HD * HD) / 1024, 256, 0, stream>>>(wv_bf, wv, HD * HD);
  conv_f2b<<<(ID * HD) / 1024, 256, 0, stream>>>(W0_bf, w0i, ID * HD);
  conv_f2b<<<(HD * ID) / 1024, 256, 0, stream>>>(W1_bf, w1i, HD * ID);
  dots_kernel<<<256, 256, 0, stream>>>(x, aw, tw, ew, dotA, dotT, dotE);
  coeff_kernel<<<1, 256, 0, stream>>>(dotA, dotT, dotE, betaA, etaA, thetaA);
  // batched k/v projections over all 16384 rows: z=0 -> zk_all (raw bf16), z=1 -> v_all (silu bf16)
  gemm128_t<2, true><<<dim3(HD / 128, (NB * SEQ) / 128, 2), 256, 0, stream>>>(
      nullptr, zk_all, v_all, nullptr, x, wk_bf, wv_bf, NB * SEQ, HD, HD);
  post_norm<true><<<NB * SEQ, 256, 0, stream>>>(k_all, nullptr, zk_all, kn);
  // state init (after zk_all is dead — it aliases surp/G)
  hipMemcpyAsync(memW0, w0i, (size_t)ID * HD * 4, hipMemcpyDeviceToDevice, stream);
  hipMemcpyAsync(memW1, w1i, (size_t)HD * ID * 4, hipMemcpyDeviceToDevice, stream);
  hipMemcpyAsync(memLn, lni, (size_t)HD * 4, hipMemcpyDeviceToDevice, stream);
  hipMemsetAsync(surpW0, 0, ((size_t)ID * HD * 2 + HD + 64) * 4, stream);
  hipMemsetAsync(nsq, 0, 64 * 4, stream);

  // ---- sequential scan (6 dispatches per chunk) ----
  for (int c = 0; c < NCHUNK; ++c) {
    gemm64_fwd<<<dim3(ID / 64, ROWS / 64), 256, 0, stream>>>(
        zfw, hfw_bf, k_all, W0_bf, ID, HD, c);
    gemm_y32<<<dim3(HD / 64, ROWS / 32), 128, 0, stream>>>(ybuf, hfw_bf, W1_bf, HD, ID);
    loss_grad<<<ROWS, 256, 0, stream>>>(ybuf, k_all, v_all, memLn, thetaA, c, gbuf, dY_bf, srow);
    gemm64_dh<<<dim3(ID / 64, ROWS / 64), 256, 0, stream>>>(
        dH_bf, dY_bf, W1_bf, zfw, ID, HD);
    gemm_grads<<<1056, 256, 0, stream>>>(
        Gw1, dY_bf, hfw_bf, Gw0, dH_bf, k_all, c, gbuf, ybuf, srow, Gln, nsq + c);
    update_all<<<2049, 256, 0, stream>>>(
        memW0, surpW0, Gw0, W0_bf, memW1, surpW1, Gw1, W1_bf,
        memLn, surpLn, Gln, etaA, betaA, c, nsq + c);
  }

  // ---- retrieval: 4 blocks of 4096 rows; alias dead scan buffers ----
  const int RB = 4096;
  float* zq    = surpW0;        // 4M f32 (surpW0+surpW1)
  u16*   qb_bf = (u16*)zfw;     // 4M u16 (zfw+ybuf+gbuf)
  u16*   h_bf  = k_all;         // 8M u16 of k_all's 16M
  float* y2    = Gw0;           // 4M f32 (Gw0+Gw1)
  for (int blk = 0; blk < (NB * SEQ) / RB; ++blk) {
    const float* xb = x + (size_t)blk * RB * HD;
    gemm128_t<0, true><<<dim3(HD / 128, RB / 128), 256, 0, stream>>>(
        zq, nullptr, nullptr, nullptr, xb, wq_bf, nullptr, RB, HD, HD);
    post_norm<false><<<RB, 256, 0, stream>>>(qb_bf, zq, nullptr, qn);
    gemm128_t<1, false><<<dim3(ID / 128, RB / 128), 256, 0, stream>>>(
        nullptr, h_bf, nullptr, qb_bf, nullptr, W0_bf, nullptr, RB, ID, HD);
    gemm128_t<0, false><<<dim3(HD / 128, RB / 128), 256, 0, stream>>>(
        y2, nullptr, nullptr, h_bf, nullptr, W1_bf, nullptr, RB, HD, ID);
    final_out_kernel<<<RB, 256, 0, stream>>>(out + (size_t)blk * RB * HD, zq, y2, qn, memLn);
  }
}

// Round 3
// 3105.609 us; speedup vs baseline: 1.6244x; 1.1909x over previous
//
#include <hip/hip_runtime.h>

#define HD 1024
#define ID 2048
#define NCHUNK 32
#define CHUNKSZ 64
#define NB 8
#define SEQ 2048
#define ROWS 512
#define MTOT 524288.0f
#define EPSF 1e-6f

typedef unsigned short u16;
typedef unsigned int u32;
typedef short bf16x8 __attribute__((ext_vector_type(8)));
typedef float f32x4 __attribute__((ext_vector_type(4)));

#define GATHER(r, c) ((((r) >> 6) * SEQ) + ((c) * CHUNKSZ) + ((r) & 63))

__device__ __forceinline__ float sigmoidf_(float x) { return 1.f / (1.f + expf(-x)); }
__device__ __forceinline__ float siluf_(float x)    { return x / (1.f + expf(-x)); }
__device__ __forceinline__ float silu_d_(float z)   { float sg = sigmoidf_(z); return sg * (1.f + z * (1.f - sg)); }

__device__ __forceinline__ u16 f2b(float f) {
  union { float f; u32 u; } v; v.f = f;
  return (u16)((v.u + 0x7fffu + ((v.u >> 16) & 1u)) >> 16);
}
__device__ __forceinline__ float b2f(u16 b) {
  union { u32 u; float f; } v; v.u = ((u32)b) << 16; return v.f;
}
__device__ __forceinline__ u32 pack2(float a, float b) { return (u32)f2b(a) | ((u32)f2b(b) << 16); }

__device__ __forceinline__ float block_reduce_sum(float v, float* s4) {
  #pragma unroll
  for (int off = 32; off > 0; off >>= 1) v += __shfl_down(v, off);
  int lane = threadIdx.x & 63, wid = threadIdx.x >> 6;
  if (lane == 0) s4[wid] = v;
  __syncthreads();
  float r = s4[0] + s4[1] + s4[2] + s4[3];
  __syncthreads();
  return r;
}

// ---------------------------------------------------------------------------
// LDS staging: NT = row-major uint4 store; TN = scatter-transpose (16 u16).
// LDS layout identical either way: [tile_row][k], stride 72 u16.
// ---------------------------------------------------------------------------
template<bool T>
__device__ __forceinline__ void stage64(u16* S, int srow, int c16, const uint4& r0, const uint4& r1) {
  if (!T) {
    *(uint4*)(S + srow * 72 + c16)     = r0;
    *(uint4*)(S + srow * 72 + c16 + 8) = r1;
  } else {
    const u16* e0 = (const u16*)&r0;
    const u16* e1 = (const u16*)&r1;
    #pragma unroll
    for (int e = 0; e < 8; ++e) S[(c16 + e) * 72 + srow] = e0[e];
    #pragma unroll
    for (int e = 0; e < 8; ++e) S[(c16 + 8 + e) * 72 + srow] = e1[e];
  }
}

// ---------------------------------------------------------------------------
// 4-wave 64x64 BK=64 core (used by gemm_grads; 4+ blocks/CU there).
// ---------------------------------------------------------------------------
template<bool AT, bool BT>
__device__ __forceinline__ void gemm64_db(
    f32x4 (&acc)[2][2], const u16* __restrict__ A, const u16* __restrict__ B,
    int K, int m0, int n0, int lda, int ldb, int chA, int chB,
    u16* As, u16* Bs)
{
  const int tid = threadIdx.x;
  const int lane = tid & 63, wave = tid >> 6;
  const int wr = wave >> 1, wc = wave & 1;
  const int l15 = lane & 15, q = lane >> 4;
  const int srow = tid >> 2, c16 = (tid & 3) * 16;

  const u16* Ap; size_t Astep;
  if (!AT) {
    int r = m0 + srow;
    if (chA >= 0) r = GATHER(r, chA);
    Ap = A + (size_t)r * lda + c16;
    Astep = 64;
  } else {
    Ap = A + (size_t)srow * lda + m0 + c16;
    Astep = (size_t)64 * lda;
  }
  const u16* Bp; size_t Bstep;
  if (!BT) {
    Bp = B + (size_t)(n0 + srow) * ldb + c16;
    Bstep = 64;
  } else {
    if (chB >= 0) { Bp = B + ((size_t)chB * CHUNKSZ + srow) * ldb + n0 + c16; Bstep = (size_t)SEQ * ldb; }
    else          { Bp = B + (size_t)srow * ldb + n0 + c16;                   Bstep = (size_t)64 * ldb; }
  }

  uint4 ra0 = *(const uint4*)Ap, ra1 = *(const uint4*)(Ap + 8);
  uint4 rb0 = *(const uint4*)Bp, rb1 = *(const uint4*)(Bp + 8);
  stage64<AT>(As, srow, c16, ra0, ra1);
  stage64<BT>(Bs, srow, c16, rb0, rb1);

  const int nt = K >> 6;
  int cur = 0;
  for (int t = 0; t < nt; ++t) {
    if (t + 1 < nt) {
      Ap += Astep; Bp += Bstep;
      ra0 = *(const uint4*)Ap; ra1 = *(const uint4*)(Ap + 8);
      rb0 = *(const uint4*)Bp; rb1 = *(const uint4*)(Bp + 8);
    }
    __syncthreads();
    const u16* Ac = As + cur * (64 * 72);
    const u16* Bc = Bs + cur * (64 * 72);
    #pragma unroll
    for (int ks = 0; ks < 2; ++ks) {
      bf16x8 af[2], bg[2];
      #pragma unroll
      for (int i = 0; i < 2; ++i) af[i] = *(const bf16x8*)&Ac[(wr * 32 + i * 16 + l15) * 72 + ks * 32 + q * 8];
      #pragma unroll
      for (int j = 0; j < 2; ++j) bg[j] = *(const bf16x8*)&Bc[(wc * 32 + j * 16 + l15) * 72 + ks * 32 + q * 8];
      #pragma unroll
      for (int i = 0; i < 2; ++i)
        #pragma unroll
        for (int j = 0; j < 2; ++j)
          acc[i][j] = __builtin_amdgcn_mfma_f32_16x16x32_bf16(af[i], bg[j], acc[i][j], 0, 0, 0);
    }
    if (t + 1 < nt) {
      stage64<AT>(As + (cur ^ 1) * (64 * 72), srow, c16, ra0, ra1);
      stage64<BT>(Bs + (cur ^ 1) * (64 * 72), srow, c16, rb0, rb1);
    }
    cur ^= 1;
  }
}

// ---------------------------------------------------------------------------
// 8-wave (512-thread) 64x64 core: in-block split-K x2 -> 2 waves/SIMD.
// Halves stage/compute independent K ranges; caller merges via LDS.
// ---------------------------------------------------------------------------
template<bool BT>
__device__ __forceinline__ void gemm64x8(
    f32x4 (&acc)[2][2], const u16* __restrict__ A, const u16* __restrict__ B,
    int K, int m0, int n0, int lda, int ldb, int chA, u16* As, u16* Bs)
{
  const int tid = threadIdx.x;
  const int half = tid >> 8;
  const int t2 = tid & 255;
  const int lane = tid & 63;
  const int w2 = t2 >> 6;
  const int wr = w2 >> 1, wc = w2 & 1;
  const int l15 = lane & 15, q = lane >> 4;
  const int srow = t2 >> 2, c16 = (t2 & 3) * 16;
  const int kbase = half * (K >> 1);

  int arow = m0 + srow;
  if (chA >= 0) arow = GATHER(arow, chA);
  const u16* Ap = A + (size_t)arow * lda + kbase + c16;
  const u16* Bp; size_t Bstep;
  if (!BT) { Bp = B + (size_t)(n0 + srow) * ldb + kbase + c16; Bstep = 64; }
  else     { Bp = B + (size_t)(kbase + srow) * ldb + n0 + c16; Bstep = (size_t)64 * ldb; }

  u16* Ah = As + half * (2 * 64 * 72);
  u16* Bh = Bs + half * (2 * 64 * 72);

  uint4 ra0 = *(const uint4*)Ap, ra1 = *(const uint4*)(Ap + 8);
  uint4 rb0 = *(const uint4*)Bp, rb1 = *(const uint4*)(Bp + 8);
  stage64<false>(Ah, srow, c16, ra0, ra1);
  stage64<BT>(Bh, srow, c16, rb0, rb1);

  const int nt = K >> 7;   // per-half K-tiles of 64
  int cur = 0;
  for (int t = 0; t < nt; ++t) {
    if (t + 1 < nt) {
      Ap += 64; Bp += Bstep;
      ra0 = *(const uint4*)Ap; ra1 = *(const uint4*)(Ap + 8);
      rb0 = *(const uint4*)Bp; rb1 = *(const uint4*)(Bp + 8);
    }
    __syncthreads();
    const u16* Ac = Ah + cur * (64 * 72);
    const u16* Bc = Bh + cur * (64 * 72);
    #pragma unroll
    for (int ks = 0; ks < 2; ++ks) {
      bf16x8 af[2], bg[2];
      #pragma unroll
      for (int i = 0; i < 2; ++i) af[i] = *(const bf16x8*)&Ac[(wr * 32 + i * 16 + l15) * 72 + ks * 32 + q * 8];
      #pragma unroll
      for (int j = 0; j < 2; ++j) bg[j] = *(const bf16x8*)&Bc[(wc * 32 + j * 16 + l15) * 72 + ks * 32 + q * 8];
      #pragma unroll
      for (int i = 0; i < 2; ++i)
        #pragma unroll
        for (int j = 0; j < 2; ++j)
          acc[i][j] = __builtin_amdgcn_mfma_f32_16x16x32_bf16(af[i], bg[j], acc[i][j], 0, 0, 0);
    }
    if (t + 1 < nt) {
      stage64<false>(Ah + (cur ^ 1) * (64 * 72), srow, c16, ra0, ra1);
      stage64<BT>(Bh + (cur ^ 1) * (64 * 72), srow, c16, rb0, rb1);
    }
    cur ^= 1;
  }
}

// fwd MLP layer-0 (512 thr): C = zfw fp32, Cb = f2b(silu(acc))
__global__ __launch_bounds__(512) void gemm64_fwd(
    float* __restrict__ C, u16* __restrict__ Cb,
    const u16* __restrict__ A, const u16* __restrict__ B, int N, int K, int chunk)
{
  __shared__ __align__(16) u16 As[2 * 2 * 64 * 72];
  __shared__ __align__(16) u16 Bs[2 * 2 * 64 * 72];
  const int m0 = blockIdx.y * 64, n0 = blockIdx.x * 64;
  f32x4 acc[2][2] = {};
  gemm64x8<false>(acc, A, B, K, m0, n0, K, K, chunk, As, Bs);
  const int tid = threadIdx.x;
  const int half = tid >> 8, t2 = tid & 255;
  const int lane = tid & 63, w2 = t2 >> 6;
  const int wr = w2 >> 1, wc = w2 & 1;
  const int l15 = lane & 15, q = lane >> 4;
  float* Cm = (float*)As;
  __syncthreads();
  if (half) {
    #pragma unroll
    for (int i = 0; i < 2; ++i)
      #pragma unroll
      for (int j = 0; j < 2; ++j)
        #pragma unroll
        for (int t = 0; t < 4; ++t)
          Cm[(wr * 32 + i * 16 + q * 4 + t) * 66 + wc * 32 + j * 16 + l15] = acc[i][j][t];
  }
  __syncthreads();
  if (!half) {
    #pragma unroll
    for (int i = 0; i < 2; ++i) {
      int r = m0 + wr * 32 + i * 16 + q * 4;
      #pragma unroll
      for (int j = 0; j < 2; ++j) {
        int col = n0 + wc * 32 + j * 16 + l15;
        #pragma unroll
        for (int t = 0; t < 4; ++t) {
          float v = acc[i][j][t] + Cm[(wr * 32 + i * 16 + q * 4 + t) * 66 + wc * 32 + j * 16 + l15];
          size_t o = (size_t)(r + t) * N + col;
          C[o] = v;
          Cb[o] = f2b(siluf_(v));
        }
      }
    }
  }
}

// dH (512 thr): Cb = f2b(acc * silu'(Z)); B = W1_bf read TN (K-major)
__global__ __launch_bounds__(512) void gemm64_dh(
    u16* __restrict__ Cb, const u16* __restrict__ A, const u16* __restrict__ B,
    const float* __restrict__ Z, int N, int K)
{
  __shared__ __align__(16) u16 As[2 * 2 * 64 * 72];
  __shared__ __align__(16) u16 Bs[2 * 2 * 64 * 72];
  const int m0 = blockIdx.y * 64, n0 = blockIdx.x * 64;
  f32x4 acc[2][2] = {};
  gemm64x8<true>(acc, A, B, K, m0, n0, K, N, -1, As, Bs);
  const int tid = threadIdx.x;
  const int half = tid >> 8, t2 = tid & 255;
  const int lane = tid & 63, w2 = t2 >> 6;
  const int wr = w2 >> 1, wc = w2 & 1;
  const int l15 = lane & 15, q = lane >> 4;
  float* Cm = (float*)As;
  __syncthreads();
  if (half) {
    #pragma unroll
    for (int i = 0; i < 2; ++i)
      #pragma unroll
      for (int j = 0; j < 2; ++j)
        #pragma unroll
        for (int t = 0; t < 4; ++t)
          Cm[(wr * 32 + i * 16 + q * 4 + t) * 66 + wc * 32 + j * 16 + l15] = acc[i][j][t];
  }
  __syncthreads();
  if (!half) {
    #pragma unroll
    for (int i = 0; i < 2; ++i) {
      int r = m0 + wr * 32 + i * 16 + q * 4;
      #pragma unroll
      for (int j = 0; j < 2; ++j) {
        int col = n0 + wc * 32 + j * 16 + l15;
        #pragma unroll
        for (int t = 0; t < 4; ++t) {
          float v = acc[i][j][t] + Cm[(wr * 32 + i * 16 + q * 4 + t) * 66 + wc * 32 + j * 16 + l15];
          size_t o = (size_t)(r + t) * N + col;
          Cb[o] = f2b(v * silu_d_(Z[o]));
        }
      }
    }
  }
}

// both weight-grad GEMMs (TN, transpose fused into staging) + Gln blocks.
__global__ __launch_bounds__(256) void gemm_grads(
    float* __restrict__ Gw1, const u16* __restrict__ dY, const u16* __restrict__ hfw,
    float* __restrict__ Gw0, const u16* __restrict__ dH, const u16* __restrict__ kall,
    int c, const float* __restrict__ g, const float* __restrict__ y,
    const float* __restrict__ srow, float* __restrict__ Gln, float* __restrict__ nsqc)
{
  __shared__ __align__(16) u16 As[2 * 64 * 72];
  __shared__ __align__(16) u16 Bs[2 * 64 * 72];
  __shared__ float s4[4];
  int bid = blockIdx.x;
  const int tid = threadIdx.x;
  if (bid >= 1024) {
    int j = (bid - 1024) * 32 + (tid & 31);
    int rg = tid >> 5;
    float acc = 0.f;
    #pragma unroll 4
    for (int i = 0; i < 64; ++i) {
      int r = rg * 64 + i;
      size_t o = (size_t)r * HD + j;
      acc += g[o] * y[o] * srow[r];
    }
    float* part = (float*)As;
    part[rg * 32 + (tid & 31)] = acc;
    __syncthreads();
    if (tid < 32) {
      float tot = 0.f;
      #pragma unroll
      for (int k = 0; k < 8; ++k) tot += part[k * 32 + tid];
      Gln[j] = tot;
      float sq = tot * tot;
      #pragma unroll
      for (int off = 16; off > 0; off >>= 1) sq += __shfl_down(sq, off);
      if (tid == 0) atomicAdd(nsqc, sq);
    }
    return;
  }
  float* C; const u16* A; const u16* B; int N, m0, n0, lda, ldb, chB;
  if (bid < 512) { A = dY; B = hfw;  C = Gw1; N = ID; lda = HD; ldb = ID; chB = -1; m0 = (bid >> 5) * 64; n0 = (bid & 31) * 64; }
  else { bid -= 512; A = dH; B = kall; C = Gw0; N = HD; lda = ID; ldb = HD; chB = c; m0 = (bid >> 4) * 64; n0 = (bid & 15) * 64; }
  f32x4 acc[2][2] = {};
  gemm64_db<true, true>(acc, A, B, ROWS, m0, n0, lda, ldb, -1, chB, As, Bs);
  const int lane = tid & 63, wave = tid >> 6;
  const int wr = wave >> 1, wc = wave & 1;
  const int l15 = lane & 15, q = lane >> 4;
  float ssq = 0.f;
  #pragma unroll
  for (int i = 0; i < 2; ++i) {
    int r = m0 + wr * 32 + i * 16 + q * 4;
    #pragma unroll
    for (int j = 0; j < 2; ++j) {
      int col = n0 + wc * 32 + j * 16 + l15;
      #pragma unroll
      for (int t = 0; t < 4; ++t) {
        float v = acc[i][j][t];
        C[(size_t)(r + t) * N + col] = v;
        ssq += v * v;
      }
    }
  }
  float tot = block_reduce_sum(ssq, s4);
  if (tid == 0) atomicAdd(nsqc, tot);
}

// 32x64-tile NT GEMM, 512 thr, in-block split-K x4: y = hfw @ W1^T (K=2048)
__global__ __launch_bounds__(512) void gemm_y32(
    float* __restrict__ C, const u16* __restrict__ A, const u16* __restrict__ B,
    int N, int K)
{
  __shared__ __align__(16) u16 As[4 * 2 * 32 * 72];
  __shared__ __align__(16) u16 Bs[4 * 2 * 64 * 72];
  const int tid = threadIdx.x;
  const int qt = tid >> 7;           // K-quarter
  const int t2 = tid & 127;
  const int lane = tid & 63;
  const int wc = t2 >> 6;
  const int l15 = lane & 15, q = lane >> 4;
  const int m0 = blockIdx.y * 32, n0 = blockIdx.x * 64;
  const int kbase = qt * (K >> 2);

  const int arow = t2 >> 2, ac16 = (t2 & 3) * 16;   // 32 rows x 64 cols
  const int brow = t2 >> 1, bc32 = (t2 & 1) * 32;   // 64 rows x 64 cols
  const u16* Ap = A + (size_t)(m0 + arow) * K + kbase + ac16;
  const u16* Bp = B + (size_t)(n0 + brow) * K + kbase + bc32;
  u16* Aq = As + qt * (2 * 32 * 72);
  u16* Bq = Bs + qt * (2 * 64 * 72);

  uint4 ra0 = *(const uint4*)Ap, ra1 = *(const uint4*)(Ap + 8);
  uint4 rb0 = *(const uint4*)Bp, rb1 = *(const uint4*)(Bp + 8);
  uint4 rb2 = *(const uint4*)(Bp + 16), rb3 = *(const uint4*)(Bp + 24);
  {
    u16* Aw = Aq + arow * 72 + ac16;
    u16* Bw = Bq + brow * 72 + bc32;
    *(uint4*)Aw = ra0; *(uint4*)(Aw + 8) = ra1;
    *(uint4*)Bw = rb0; *(uint4*)(Bw + 8) = rb1;
    *(uint4*)(Bw + 16) = rb2; *(uint4*)(Bw + 24) = rb3;
  }

  f32x4 acc[2][2] = {};
  const int nt = K >> 8;             // per-quarter tiles of 64
  int cur = 0;
  for (int t = 0; t < nt; ++t) {
    if (t + 1 < nt) {
      Ap += 64; Bp += 64;
      ra0 = *(const uint4*)Ap; ra1 = *(const uint4*)(Ap + 8);
      rb0 = *(const uint4*)Bp; rb1 = *(const uint4*)(Bp + 8);
      rb2 = *(const uint4*)(Bp + 16); rb3 = *(const uint4*)(Bp + 24);
    }
    __syncthreads();
    const u16* Ac = Aq + cur * (32 * 72);
    const u16* Bc = Bq + cur * (64 * 72);
    #pragma unroll
    for (int ks = 0; ks < 2; ++ks) {
      bf16x8 af[2], bg[2];
      #pragma unroll
      for (int i = 0; i < 2; ++i) af[i] = *(const bf16x8*)&Ac[(i * 16 + l15) * 72 + ks * 32 + q * 8];
      #pragma unroll
      for (int j = 0; j < 2; ++j) bg[j] = *(const bf16x8*)&Bc[(wc * 32 + j * 16 + l15) * 72 + ks * 32 + q * 8];
      #pragma unroll
      for (int i = 0; i < 2; ++i)
        #pragma unroll
        for (int j = 0; j < 2; ++j)
          acc[i][j] = __builtin_amdgcn_mfma_f32_16x16x32_bf16(af[i], bg[j], acc[i][j], 0, 0, 0);
    }
    if (t + 1 < nt) {
      u16* Aw = Aq + (cur ^ 1) * (32 * 72) + arow * 72 + ac16;
      u16* Bw = Bq + (cur ^ 1) * (64 * 72) + brow * 72 + bc32;
      *(uint4*)Aw = ra0; *(uint4*)(Aw + 8) = ra1;
      *(uint4*)Bw = rb0; *(uint4*)(Bw + 8) = rb1;
      *(uint4*)(Bw + 16) = rb2; *(uint4*)(Bw + 24) = rb3;
    }
    cur ^= 1;
  }
  // merge: quarters 1..3 dump to LDS, quarter 0 reduces + writes
  float* Cm = (float*)As;  // 3 x 32 x 66 f32 = 25,344 B <= 36,864
  __syncthreads();
  if (qt) {
    #pragma unroll
    for (int i = 0; i < 2; ++i)
      #pragma unroll
      for (int j = 0; j < 2; ++j)
        #pragma unroll
        for (int t = 0; t < 4; ++t)
          Cm[((qt - 1) * 32 + i * 16 + q * 4 + t) * 66 + wc * 32 + j * 16 + l15] = acc[i][j][t];
  }
  __syncthreads();
  if (!qt) {
    #pragma unroll
    for (int i = 0; i < 2; ++i) {
      int r = m0 + i * 16 + q * 4;
      #pragma unroll
      for (int j = 0; j < 2; ++j) {
        int col = n0 + wc * 32 + j * 16 + l15;
        #pragma unroll
        for (int t = 0; t < 4; ++t) {
          float v = acc[i][j][t];
          #pragma unroll
          for (int p = 0; p < 3; ++p)
            v += Cm[(p * 32 + i * 16 + q * 4 + t) * 66 + wc * 32 + j * 16 + l15];
          C[(size_t)(r + t) * N + col] = v;
        }
      }
    }
  }
}

// ---------------------------------------------------------------------------
// 128x128-tile BK=32 NT GEMM core (stride-40 LDS), bf16 A with stride lda.
// ---------------------------------------------------------------------------
__device__ __forceinline__ void gemm128_core(
    f32x4 (&acc)[4][4], const u16* __restrict__ A, int lda,
    const u16* __restrict__ B, int ldb, int K, int m0, int n0,
    u16* As, u16* Bs)
{
  const int tid = threadIdx.x;
  const int lane = tid & 63, wave = tid >> 6;
  const int wr = wave >> 1, wc = wave & 1;
  const int l15 = lane & 15, q = lane >> 4;
  for (int k0 = 0; k0 < K; k0 += 32) {
    #pragma unroll
    for (int it = 0; it < 2; ++it) {
      int cid = tid + it * 256;
      int row = cid >> 2, c8 = (cid & 3) * 8;
      *(uint4*)&As[row * 40 + c8] = *(const uint4*)&A[(size_t)(m0 + row) * lda + k0 + c8];
      *(uint4*)&Bs[row * 40 + c8] = *(const uint4*)&B[(size_t)(n0 + row) * ldb + k0 + c8];
    }
    __syncthreads();
    bf16x8 af[4], bg[4];
    #pragma unroll
    for (int i = 0; i < 4; ++i) af[i] = *(const bf16x8*)&As[(wr * 64 + i * 16 + l15) * 40 + q * 8];
    #pragma unroll
    for (int j = 0; j < 4; ++j) bg[j] = *(const bf16x8*)&Bs[(wc * 64 + j * 16 + l15) * 40 + q * 8];
    #pragma unroll
    for (int i = 0; i < 4; ++i)
      #pragma unroll
      for (int j = 0; j < 4; ++j)
        acc[i][j] = __builtin_amdgcn_mfma_f32_16x16x32_bf16(af[i], bg[j], acc[i][j], 0, 0, 0);
    __syncthreads();
  }
}

// setup batched q/k/v projection; XCD-chunked swizzle (panel -> one XCD).
// z=0: k raw bf16; z=1: v silu bf16; z=2: zq raw f32 (into out buffer).
__global__ __launch_bounds__(256) void gemm_qkv(
    float* __restrict__ zqC, u16* __restrict__ kC, u16* __restrict__ vC,
    const u16* __restrict__ xb, const u16* __restrict__ wk,
    const u16* __restrict__ wv, const u16* __restrict__ wq)
{
  __shared__ __align__(16) u16 As[128 * 40];
  __shared__ __align__(16) u16 Bs[128 * 40];
  int f = blockIdx.x;                 // 3072 = 8 xcd * 16 panel-groups * 24
  int xcd = f & 7, jj = f >> 3;
  int panel = xcd + 8 * (jj / 24);    // 0..127
  int w = jj % 24;
  int z = w >> 3, xt = w & 7;
  int m0 = panel * 128, n0 = xt * 128;
  const u16* B = (z == 0) ? wk : ((z == 1) ? wv : wq);
  f32x4 acc[4][4] = {};
  gemm128_core(acc, xb, HD, B, HD, HD, m0, n0, As, Bs);
  const int tid = threadIdx.x;
  const int lane = tid & 63, wave = tid >> 6;
  const int wr = wave >> 1, wc = wave & 1;
  const int l15 = lane & 15, q = lane >> 4;
  #pragma unroll
  for (int i = 0; i < 4; ++i) {
    int r = m0 + wr * 64 + i * 16 + q * 4;
    #pragma unroll
    for (int j = 0; j < 4; ++j) {
      int col = n0 + wc * 64 + j * 16 + l15;
      #pragma unroll
      for (int t = 0; t < 4; ++t) {
        float v = acc[i][j][t];
        size_t o = (size_t)(r + t) * HD + col;
        if (z == 0) kC[o] = f2b(v);
        else if (z == 1) vC[o] = f2b(siluf_(v));
        else zqC[o] = v;
      }
    }
  }
}

// retrieval h = silu(qb @ W0^T), 8192 rows per launch, swizzled
__global__ __launch_bounds__(256) void gemm_h(
    u16* __restrict__ hC, const u16* __restrict__ A, const u16* __restrict__ B)
{
  __shared__ __align__(16) u16 As[128 * 40];
  __shared__ __align__(16) u16 Bs[128 * 40];
  int f = blockIdx.x;                 // 1024 = 8 xcd * 8 panel-groups * 16
  int xcd = f & 7, jj = f >> 3;
  int panel = xcd + 8 * (jj >> 4);    // 0..63
  int xt = jj & 15;
  int m0 = panel * 128, n0 = xt * 128;
  f32x4 acc[4][4] = {};
  gemm128_core(acc, A, HD, B, HD, HD, m0, n0, As, Bs);
  const int tid = threadIdx.x;
  const int lane = tid & 63, wave = tid >> 6;
  const int wr = wave >> 1, wc = wave & 1;
  const int l15 = lane & 15, q = lane >> 4;
  #pragma unroll
  for (int i = 0; i < 4; ++i) {
    int r = m0 + wr * 64 + i * 16 + q * 4;
    #pragma unroll
    for (int j = 0; j < 4; ++j) {
      int col = n0 + wc * 64 + j * 16 + l15;
      #pragma unroll
      for (int t = 0; t < 4; ++t)
        hC[(size_t)(r + t) * ID + col] = f2b(siluf_(acc[i][j][t]));
    }
  }
}

// retrieval y2 = h @ W1^T (K=2048), swizzled
__global__ __launch_bounds__(256) void gemm_y2(
    float* __restrict__ C, const u16* __restrict__ A, const u16* __restrict__ B)
{
  __shared__ __align__(16) u16 As[128 * 40];
  __shared__ __align__(16) u16 Bs[128 * 40];
  int f = blockIdx.x;                 // 512 = 8 xcd * 8 panel-groups * 8
  int xcd = f & 7, jj = f >> 3;
  int panel = xcd + 8 * (jj >> 3);    // 0..63
  int xt = jj & 7;
  int m0 = panel * 128, n0 = xt * 128;
  f32x4 acc[4][4] = {};
  gemm128_core(acc, A, ID, B, ID, ID, m0, n0, As, Bs);
  const int tid = threadIdx.x;
  const int lane = tid & 63, wave = tid >> 6;
  const int wr = wave >> 1, wc = wave & 1;
  const int l15 = lane & 15, q = lane >> 4;
  #pragma unroll
  for (int i = 0; i < 4; ++i) {
    int r = m0 + wr * 64 + i * 16 + q * 4;
    #pragma unroll
    for (int j = 0; j < 4; ++j) {
      int col = n0 + wc * 64 + j * 16 + l15;
      #pragma unroll
      for (int t = 0; t < 4; ++t)
        C[(size_t)(r + t) * HD + col] = acc[i][j][t];
    }
  }
}

// ---------------------------------------------------------------------------
// setup conversions
// ---------------------------------------------------------------------------
__global__ __launch_bounds__(256) void conv_f2b(u16* __restrict__ dst, const float* __restrict__ src, int n) {
  int i = (blockIdx.x * 256 + threadIdx.x) * 4;
  if (i < n) {
    float4 v = *(const float4*)&src[i];
    uint2 o; o.x = pack2(v.x, v.y); o.y = pack2(v.z, v.w);
    *(uint2*)&dst[i] = o;
  }
}

// ---------------------------------------------------------------------------
// small fused kernels
// ---------------------------------------------------------------------------
__global__ __launch_bounds__(256) void dots_kernel(
    const float* __restrict__ x, const float* __restrict__ aw,
    const float* __restrict__ tw, const float* __restrict__ ew,
    float* __restrict__ dA, float* __restrict__ dT, float* __restrict__ dE)
{
  int b = blockIdx.x >> 5, c = blockIdx.x & 31;
  const float* base = x + ((size_t)b * SEQ + (size_t)c * CHUNKSZ) * HD;
  float a = 0.f, t = 0.f, e = 0.f;
  for (int it = 0; it < 64; ++it) {
    int j = (it * 256 + threadIdx.x) * 4;
    float4 xv = *(const float4*)&base[j];
    float4 av = *(const float4*)&aw[j];
    float4 tv = *(const float4*)&tw[j];
    float4 ev = *(const float4*)&ew[j];
    a += xv.x * av.x + xv.y * av.y + xv.z * av.z + xv.w * av.w;
    t += xv.x * tv.x + xv.y * tv.y + xv.z * tv.z + xv.w * tv.w;
    e += xv.x * ev.x + xv.y * ev.y + xv.z * ev.z + xv.w * ev.w;
  }
  __shared__ float s4[4];
  a = block_reduce_sum(a, s4);
  t = block_reduce_sum(t, s4);
  e = block_reduce_sum(e, s4);
  if (threadIdx.x == 0) { dA[blockIdx.x] = a; dT[blockIdx.x] = t; dE[blockIdx.x] = e; }
}

__global__ __launch_bounds__(256) void coeff_kernel(
    const float* __restrict__ dA, const float* __restrict__ dT, const float* __restrict__ dE,
    float* __restrict__ betaA, float* __restrict__ etaA, float* __restrict__ thetaA)
{
  int t = threadIdx.x;
  if (t < 256) thetaA[t] = sigmoidf_(dT[t]) * 0.01f;
  if (t < 32) {
    float sa = 0.f, se = 0.f;
    for (int b = 0; b < NB; ++b) { sa += dA[b * 32 + t]; se += dE[b * 32 + t]; }
    betaA[t] = 1.f - sigmoidf_(sa / 8.f);
    etaA[t]  = sigmoidf_(se / 8.f);
  }
}

// in-place bf16: buf = f2b(rmsnorm(silu(b2f(buf))) * nw)
__global__ __launch_bounds__(256) void post_norm_kb(u16* buf, const float* __restrict__ nw)
{
  size_t off = (size_t)blockIdx.x * HD;
  float sv[4]; float ss = 0.f;
  #pragma unroll
  for (int i = 0; i < 4; ++i) {
    int j = i * 256 + threadIdx.x;
    float s = siluf_(b2f(buf[off + j]));
    sv[i] = s; ss += s * s;
  }
  __shared__ float s4[4];
  ss = block_reduce_sum(ss, s4);
  float rs = rsqrtf(ss / (float)HD + EPSF);
  #pragma unroll
  for (int i = 0; i < 4; ++i) {
    int j = i * 256 + threadIdx.x;
    buf[off + j] = f2b(sv[i] * rs * nw[j]);
  }
}

// in-place f32: buf = rmsnorm(silu(buf)) * nw
__global__ __launch_bounds__(256) void post_norm_qf(float* buf, const float* __restrict__ nw)
{
  size_t off = (size_t)blockIdx.x * HD;
  float sv[4]; float ss = 0.f;
  #pragma unroll
  for (int i = 0; i < 4; ++i) {
    int j = i * 256 + threadIdx.x;
    float s = siluf_(buf[off + j]);
    sv[i] = s; ss += s * s;
  }
  __shared__ float s4[4];
  ss = block_reduce_sum(ss, s4);
  float rs = rsqrtf(ss / (float)HD + EPSF);
  #pragma unroll
  for (int i = 0; i < 4; ++i) {
    int j = i * 256 + threadIdx.x;
    buf[off + j] = sv[i] * rs * nw[j];
  }
}

// per-row loss grad: k,v read as bf16 (gathered rows of k_all/v_all)
__global__ __launch_bounds__(256) void loss_grad(
    const float* __restrict__ y, const u16* __restrict__ kall, const u16* __restrict__ vall,
    const float* __restrict__ ln, const float* __restrict__ thetaA, int c,
    float* __restrict__ g, u16* __restrict__ dYbf, float* __restrict__ srow)
{
  int r = blockIdx.x;
  size_t off = (size_t)r * HD;
  size_t goff = (size_t)GATHER(r, c) * HD;
  float th = thetaA[(r >> 6) * 32 + c];
  float yv[4], lnv[4];
  float ss = 0.f;
  #pragma unroll
  for (int i = 0; i < 4; ++i) {
    int j = i * 256 + threadIdx.x;
    yv[i] = y[off + j];
    lnv[i] = ln[j];
    ss += yv[i] * yv[i];
  }
  __shared__ float s4[4];
  ss = block_reduce_sum(ss, s4);
  float s = rsqrtf(ss / (float)HD + EPSF);
  float coef = 2.f * th / MTOT;
  float gv[4]; float t = 0.f;
  #pragma unroll
  for (int i = 0; i < 4; ++i) {
    int j = i * 256 + threadIdx.x;
    float pred = b2f(kall[goff + j]) + yv[i] * s * lnv[i];
    float gg = coef * (pred - b2f(vall[goff + j]));
    gv[i] = gg;
    g[off + j] = gg;
    t += gg * lnv[i] * yv[i];
  }
  t = block_reduce_sum(t, s4);
  float c3 = s * s * s * t * (1.f / (float)HD);
  #pragma unroll
  for (int i = 0; i < 4; ++i) {
    int j = i * 256 + threadIdx.x;
    dYbf[off + j] = f2b(s * gv[i] * lnv[i] - c3 * yv[i]);
  }
  if (threadIdx.x == 0) srow[r] = s;
}

// merged update, flat: blocks [0,1024)=W1 (+w1b), [1024,2048)=W0 (+w0b), 2048=ln
__global__ __launch_bounds__(256) void update_all(
    float* __restrict__ mw0, float* __restrict__ sw0, const float* __restrict__ g0, u16* __restrict__ w0b,
    float* __restrict__ mw1, float* __restrict__ sw1, const float* __restrict__ g1, u16* __restrict__ w1b,
    float* __restrict__ mln, float* __restrict__ sln, const float* __restrict__ gl,
    const float* __restrict__ etaA, const float* __restrict__ betaA, int c,
    const float* __restrict__ nsqc)
{
  float clip = fminf(1.0f / (sqrtf(*nsqc) + 1e-6f), 1.0f);
  float eta = etaA[c], beta = betaA[c];
  int bid = blockIdx.x;
  if (bid < 2048) {
    float* mw; float* sw; const float* g; u16* wb; size_t i0;
    if (bid < 1024) { mw = mw1; sw = sw1; g = g1; wb = w1b; i0 = (size_t)bid * 2048; }
    else            { mw = mw0; sw = sw0; g = g0; wb = w0b; i0 = (size_t)(bid - 1024) * 2048; }
    i0 += (size_t)threadIdx.x * 8;
    u16 bb[8];
    #pragma unroll
    for (int h = 0; h < 2; ++h) {
      size_t i = i0 + h * 4;
      float4 s = *(float4*)&sw[i];
      float4 gg = *(const float4*)&g[i];
      float4 m = *(float4*)&mw[i];
      s.x = eta * s.x - clip * gg.x; m.x = beta * m.x + s.x;
      s.y = eta * s.y - clip * gg.y; m.y = beta * m.y + s.y;
      s.z = eta * s.z - clip * gg.z; m.z = beta * m.z + s.z;
      s.w = eta * s.w - clip * gg.w; m.w = beta * m.w + s.w;
      *(float4*)&sw[i] = s;
      *(float4*)&mw[i] = m;
      bb[h * 4 + 0] = f2b(m.x); bb[h * 4 + 1] = f2b(m.y);
      bb[h * 4 + 2] = f2b(m.z); bb[h * 4 + 3] = f2b(m.w);
    }
    *(uint4*)&wb[i0] = *(uint4*)bb;
  } else {
    int i = threadIdx.x * 4;
    #pragma unroll
    for (int k = 0; k < 4; ++k) {
      float ns = eta * sln[i + k] - clip * gl[i + k];
      sln[i + k] = ns;
      mln[i + k] = beta * mln[i + k] + ns;
    }
  }
}

// out = q(already in out) + rmsnorm(y2)*ln; in-place on out
__global__ __launch_bounds__(256) void final_out_kernel(
    float* outp, const float* __restrict__ y2, const float* __restrict__ ln)
{
  size_t off = (size_t)blockIdx.x * HD;
  float qv[4], yv[4];
  float ss2 = 0.f;
  #pragma unroll
  for (int i = 0; i < 4; ++i) {
    int j = i * 256 + threadIdx.x;
    qv[i] = outp[off + j];
    yv[i] = y2[off + j];
    ss2 += yv[i] * yv[i];
  }
  __shared__ float s4[4];
  ss2 = block_reduce_sum(ss2, s4);
  float rs2 = rsqrtf(ss2 / (float)HD + EPSF);
  #pragma unroll
  for (int i = 0; i < 4; ++i) {
    int j = i * 256 + threadIdx.x;
    outp[off + j] = qv[i] + yv[i] * rs2 * ln[j];
  }
}

// ---------------------------------------------------------------------------
// launch
// ---------------------------------------------------------------------------
extern "C" void kernel_launch(void* const* d_in, const int* in_sizes, int n_in,
                              void* d_out, int out_size, void* d_ws, size_t ws_size,
                              hipStream_t stream) {
  const float* x   = (const float*)d_in[0];
  const float* wq  = (const float*)d_in[1];
  const float* wk  = (const float*)d_in[2];
  const float* wv  = (const float*)d_in[3];
  const float* qn  = (const float*)d_in[4];
  const float* kn  = (const float*)d_in[5];
  const float* aw  = (const float*)d_in[6];
  const float* tw  = (const float*)d_in[7];
  const float* ew  = (const float*)d_in[8];
  const float* w0i = (const float*)d_in[9];
  const float* w1i = (const float*)d_in[10];
  const float* lni = (const float*)d_in[11];
  float* out = (float*)d_out;

  float* p = (float*)d_ws;
  auto alloc = [&](size_t n) { n = (n + 63) & ~(size_t)63; float* r = p; p += n; return r; };
  // order matters: memW0..surpW1 (32 MiB) aliases x_bf during setup;
  // surpW0..Gw1 (32 MiB) aliases y2 during retrieval.
  float* memW0  = alloc((size_t)ID * HD);
  float* memW1  = alloc((size_t)HD * ID);
  float* surpW0 = alloc((size_t)ID * HD);
  float* surpW1 = alloc((size_t)HD * ID);
  float* Gw0    = alloc((size_t)ID * HD);
  float* Gw1    = alloc((size_t)HD * ID);
  float* memLn  = alloc(HD);
  float* surpLn = alloc(HD);
  float* Gln    = alloc(HD);
  float* zfw    = alloc((size_t)ROWS * ID);
  float* ybuf   = alloc((size_t)ROWS * HD);
  float* gbuf   = alloc((size_t)ROWS * HD);
  float* srow   = alloc(ROWS);
  float* dotA   = alloc(256);
  float* dotT   = alloc(256);
  float* dotE   = alloc(256);
  float* betaA  = alloc(64);
  float* etaA   = alloc(64);
  float* thetaA = alloc(256);
  float* nsq    = alloc(64);

  u16* bp = (u16*)p;
  auto balloc = [&](size_t n) { n = (n + 63) & ~(size_t)63; u16* r = bp; bp += n; return r; };
  u16* wq_bf  = balloc((size_t)HD * HD);
  u16* wk_bf  = balloc((size_t)HD * HD);
  u16* wv_bf  = balloc((size_t)HD * HD);
  u16* W0_bf  = balloc((size_t)ID * HD);
  u16* W1_bf  = balloc((size_t)HD * ID);
  u16* k_all  = balloc((size_t)NB * SEQ * HD);  // also: qb_bf (retrieval)
  u16* v_all  = balloc((size_t)NB * SEQ * HD);  // also: h_bf (retrieval)
  u16* hfw_bf = balloc((size_t)ROWS * ID);
  u16* dY_bf  = balloc((size_t)ROWS * HD);
  u16* dH_bf  = balloc((size_t)ROWS * ID);
  size_t needed = (size_t)((char*)bp - (char*)d_ws);
  if (needed > ws_size) return;

  u16* x_bf = (u16*)memW0;   // 32 MiB = memW0..surpW1; dead before memcpy/memset

  // ---- setup ----
  conv_f2b<<<(HD * HD) / 1024, 256, 0, stream>>>(wq_bf, wq, HD * HD);
  conv_f2b<<<(HD * HD) / 1024, 256, 0, stream>>>(wk_bf, wk, HD * HD);
  conv_f2b<<<(HD * HD) / 1024, 256, 0, stream>>>(wv_bf, wv, HD * HD);
  conv_f2b<<<(ID * HD) / 1024, 256, 0, stream>>>(W0_bf, w0i, ID * HD);
  conv_f2b<<<(HD * ID) / 1024, 256, 0, stream>>>(W1_bf, w1i, HD * ID);
  conv_f2b<<<(NB * SEQ * HD) / 1024, 256, 0, stream>>>(x_bf, x, NB * SEQ * HD);
  dots_kernel<<<256, 256, 0, stream>>>(x, aw, tw, ew, dotA, dotT, dotE);
  coeff_kernel<<<1, 256, 0, stream>>>(dotA, dotT, dotE, betaA, etaA, thetaA);
  // batched q/k/v over all 16384 rows (XCD-swizzled): k raw->k_all, v silu->v_all, zq f32->out
  gemm_qkv<<<3072, 256, 0, stream>>>(out, k_all, v_all, x_bf, wk_bf, wv_bf, wq_bf);
  post_norm_kb<<<NB * SEQ, 256, 0, stream>>>(k_all, kn);   // k in-place norm
  post_norm_qf<<<NB * SEQ, 256, 0, stream>>>(out, qn);     // q in-place norm (f32, stays in out)
  // state init (x_bf dead now)
  hipMemcpyAsync(memW0, w0i, (size_t)ID * HD * 4, hipMemcpyDeviceToDevice, stream);
  hipMemcpyAsync(memW1, w1i, (size_t)HD * ID * 4, hipMemcpyDeviceToDevice, stream);
  hipMemcpyAsync(memLn, lni, (size_t)HD * 4, hipMemcpyDeviceToDevice, stream);
  hipMemsetAsync(surpW0, 0, (size_t)ID * HD * 2 * 4, stream);
  hipMemsetAsync(surpLn, 0, HD * 4, stream);
  hipMemsetAsync(nsq, 0, 64 * 4, stream);

  // ---- sequential scan (6 dispatches per chunk) ----
  for (int c = 0; c < NCHUNK; ++c) {
    gemm64_fwd<<<dim3(ID / 64, ROWS / 64), 512, 0, stream>>>(
        zfw, hfw_bf, k_all, W0_bf, ID, HD, c);
    gemm_y32<<<dim3(HD / 64, ROWS / 32), 512, 0, stream>>>(ybuf, hfw_bf, W1_bf, HD, ID);
    loss_grad<<<ROWS, 256, 0, stream>>>(ybuf, k_all, v_all, memLn, thetaA, c, gbuf, dY_bf, srow);
    gemm64_dh<<<dim3(ID / 64, ROWS / 64), 512, 0, stream>>>(
        dH_bf, dY_bf, W1_bf, zfw, ID, HD);
    gemm_grads<<<1056, 256, 0, stream>>>(
        Gw1, dY_bf, hfw_bf, Gw0, dH_bf, k_all, c, gbuf, ybuf, srow, Gln, nsq + c);
    update_all<<<2049, 256, 0, stream>>>(
        memW0, surpW0, Gw0, W0_bf, memW1, surpW1, Gw1, W1_bf,
        memLn, surpLn, Gln, etaA, betaA, c, nsq + c);
  }

  // ---- retrieval: q already normed in out; 2 blocks of 8192 rows ----
  u16*   qb_bf = k_all;          // 32 MiB, dead after scan
  u16*   h_bf  = v_all;          // 32 MiB = 8192 x 2048 u16
  float* y2    = surpW0;         // 32 MiB = surpW0..Gw1
  conv_f2b<<<(NB * SEQ * HD) / 1024, 256, 0, stream>>>(qb_bf, out, NB * SEQ * HD);
  for (int blk = 0; blk < 2; ++blk) {
    gemm_h<<<1024, 256, 0, stream>>>(h_bf, qb_bf + (size_t)blk * 8192 * HD, W0_bf);
    gemm_y2<<<512, 256, 0, stream>>>(y2, h_bf, W1_bf);
    final_out_kernel<<<8192, 256, 0, stream>>>(out + (size_t)blk * 8192 * HD, y2, memLn);
  }
}